// Round 5
// baseline (243.766 us; speedup 1.0000x reference)
//
#include <hip/hip_runtime.h>
#include <hip/hip_fp16.h>

#define DIM 128
#define KCODES 1024
#define BROWS 128                  // rows per block = 4 waves x 32 rows
#define CCHUNK 64                  // codes per LDS chunk (double-buffered)
#define NCHUNKS (KCODES / CCHUNK)  // 16
#define CH_HALFS (CCHUNK * DIM)    // 8192 halfs = 16 KB
#define TAU_ACC 1.2e-3f            // acc units (= x.e - ||e||^2/2); fp16 2-pass err ~2.8e-4 rms

typedef _Float16 f16x8 __attribute__((ext_vector_type(8)));
typedef float f32x4 __attribute__((ext_vector_type(4)));

__device__ __forceinline__ void gl_lds16(const void* g, void* l) {
    __builtin_amdgcn_global_load_lds(
        (const __attribute__((address_space(1))) void*)g,
        (__attribute__((address_space(3))) void*)l, 16, 0, 0);
}

// ---------- prep A: ||e_k||^2 (identical arithmetic to passing kernel) ----------
__global__ void enorm_kernel(const float* __restrict__ embed, float* __restrict__ enorm) {
    int k = blockIdx.x * blockDim.x + threadIdx.x;
    if (k < KCODES) {
        const float4* row = (const float4*)(embed + (size_t)k * DIM);
        float s = 0.f;
#pragma unroll
        for (int d = 0; d < DIM / 4; ++d) {
            float4 v = row[d];
            s = fmaf(v.x, v.x, s); s = fmaf(v.y, v.y, s);
            s = fmaf(v.z, v.z, s); s = fmaf(v.w, v.w, s);
        }
        enorm[k] = s;
    }
}

// ---------- prep B: E -> fp16, MFMA-fragment-ordered coalesced layout ----------
// t = c*256 + ks*64 + q*16 + n  (dst seg == t):
//   Ehp[t*8 + j] = (f16) embed[c*16 + n][ks*32 + q*8 + j]
// Lane-linear in (c,ks) -> global_load_lds staging produces a verbatim LDS image.
__global__ void pack_kernel(const float* __restrict__ embed, _Float16* __restrict__ Ehp) {
    int t = blockIdx.x * blockDim.x + threadIdx.x;   // 0 .. KCODES*16-1
    int n  = t & 15;
    int q  = (t >> 4) & 3;
    int ks = (t >> 6) & 3;
    int c  = t >> 8;
    const float* src = embed + (size_t)(c * 16 + n) * DIM + ks * 32 + q * 8;
    float4 a0 = *(const float4*)src;
    float4 a1 = *(const float4*)(src + 4);
    float f[8] = {a0.x, a0.y, a0.z, a0.w, a1.x, a1.y, a1.z, a1.w};
    f16x8 h8;
#pragma unroll
    for (int j = 0; j < 8; ++j) h8[j] = (_Float16)f[j];
    *(f16x8*)&Ehp[(size_t)t * 8] = h8;
}

// ---------- main: LDS-shared B (staged once per block), fp16 2-pass MFMA argmax ----------
// Round-5 deltas vs round-4: B goes global->LDS once per block per chunk via
// global_load_lds (4x less per-CU global traffic), MFMA B-operands come from
// conflict-free ds_read_b128. T3 minimum 2-phase: stage(next) -> compute(cur)
// -> one barrier. Math/selection/refine/gather identical to round-4 (passing).
__global__ __launch_bounds__(256, 3)
void argmax_mfma_kernel(const float* __restrict__ x, const float* __restrict__ embed,
                        const _Float16* __restrict__ Ehp, const float* __restrict__ enorm,
                        float* __restrict__ outq, float* __restrict__ outi) {
    __shared__ __align__(16) _Float16 ebuf[2][CH_HALFS];  // 2 x 16 KB
    __shared__ float enorm_l[KCODES];   // -0.5*||e||^2
    __shared__ int idx_l[BROWS];
    __shared__ int flist[BROWS];
    __shared__ float rbest[4];
    __shared__ int   rbidx[4];
    __shared__ int fcnt;

    const int tid  = threadIdx.x;
    const int w    = tid >> 6;       // wave 0..3
    const int lane = tid & 63;
    const int n    = lane & 15;      // code col / A row class
    const int q    = lane >> 4;      // k-segment (A/B) / C row group
    const size_t row0 = (size_t)blockIdx.x * BROWS;

    if (tid == 0) fcnt = 0;
    {   // enorm -> LDS as -0.5*||e||^2 (folded into MFMA C-init)
        float4 e4 = ((const float4*)enorm)[tid];
        float4 v; v.x = -0.5f * e4.x; v.y = -0.5f * e4.y; v.z = -0.5f * e4.z; v.w = -0.5f * e4.w;
        ((float4*)enorm_l)[tid] = v;
    }

    // stage chunk 0: wave w stages code-group cg=w (4 k-slices), lane-linear 1 KB each
    {
        const _Float16* gsrc = Ehp + (size_t)w * 2048 + (size_t)lane * 8;
        _Float16* ldst = &ebuf[0][w * 2048];
#pragma unroll
        for (int ks = 0; ks < 4; ++ks)
            gl_lds16(gsrc + ks * 512, ldst + ks * 512);
    }

    // A fragments: this wave's 32 rows (2 rowsets of 16), fp16 hi/lo split.
    // layout: A[m = lane&15][k = ks*32 + q*8 + j]  (geometry verified, passing)
    f16x8 xh[2][4], xl[2][4];
#pragma unroll
    for (int s = 0; s < 2; ++s)
#pragma unroll
        for (int ks = 0; ks < 4; ++ks) {
            const float* xp = x + (row0 + (size_t)(w * 32 + s * 16 + n)) * DIM + ks * 32 + q * 8;
            float4 a0 = *(const float4*)xp;
            float4 a1 = *(const float4*)(xp + 4);
            float f[8] = {a0.x, a0.y, a0.z, a0.w, a1.x, a1.y, a1.z, a1.w};
            f16x8 h, l;
#pragma unroll
            for (int j = 0; j < 8; ++j) {
                _Float16 hh = (_Float16)f[j];
                h[j] = hh;
                l[j] = (_Float16)(f[j] - (float)hh);
            }
            xh[s][ks] = h; xl[s][ks] = l;
        }

    __syncthreads();   // enorm_l ready + chunk-0 staging drained (compiler vmcnt at barrier)

    float best[2][4], sec[2][4]; int bidx[2][4];
#pragma unroll
    for (int s = 0; s < 2; ++s)
#pragma unroll
        for (int rg = 0; rg < 4; ++rg) { best[s][rg] = -3.4e38f; sec[s][rg] = -3.4e38f; bidx[s][rg] = 0; }

// one 16-code group from LDS: 4 ds_read_b128 B-frags, 4 independent MFMA chains
// of depth 4 (hi/lo split accs, merged by one add), then top-2 update.
#define PROC(CI, EBC, EV) do {                                                        \
    const int code_ = (CI) * 16 + n;                                                  \
    const _Float16* ebc_ = (EBC) + (size_t)lane * 8;                                  \
    f16x8 B0 = *(const f16x8*)(ebc_);                                                 \
    f16x8 B1 = *(const f16x8*)(ebc_ + 512);                                           \
    f16x8 B2 = *(const f16x8*)(ebc_ + 1024);                                          \
    f16x8 B3 = *(const f16x8*)(ebc_ + 1536);                                          \
    f32x4 h0 = {EV, EV, EV, EV}, l0 = {0.f, 0.f, 0.f, 0.f};                           \
    f32x4 h1 = {EV, EV, EV, EV}, l1 = {0.f, 0.f, 0.f, 0.f};                           \
    h0 = __builtin_amdgcn_mfma_f32_16x16x32_f16(xh[0][0], B0, h0, 0, 0, 0);           \
    h1 = __builtin_amdgcn_mfma_f32_16x16x32_f16(xh[1][0], B0, h1, 0, 0, 0);           \
    l0 = __builtin_amdgcn_mfma_f32_16x16x32_f16(xl[0][0], B0, l0, 0, 0, 0);           \
    l1 = __builtin_amdgcn_mfma_f32_16x16x32_f16(xl[1][0], B0, l1, 0, 0, 0);           \
    h0 = __builtin_amdgcn_mfma_f32_16x16x32_f16(xh[0][1], B1, h0, 0, 0, 0);           \
    h1 = __builtin_amdgcn_mfma_f32_16x16x32_f16(xh[1][1], B1, h1, 0, 0, 0);           \
    l0 = __builtin_amdgcn_mfma_f32_16x16x32_f16(xl[0][1], B1, l0, 0, 0, 0);           \
    l1 = __builtin_amdgcn_mfma_f32_16x16x32_f16(xl[1][1], B1, l1, 0, 0, 0);           \
    h0 = __builtin_amdgcn_mfma_f32_16x16x32_f16(xh[0][2], B2, h0, 0, 0, 0);           \
    h1 = __builtin_amdgcn_mfma_f32_16x16x32_f16(xh[1][2], B2, h1, 0, 0, 0);           \
    l0 = __builtin_amdgcn_mfma_f32_16x16x32_f16(xl[0][2], B2, l0, 0, 0, 0);           \
    l1 = __builtin_amdgcn_mfma_f32_16x16x32_f16(xl[1][2], B2, l1, 0, 0, 0);           \
    h0 = __builtin_amdgcn_mfma_f32_16x16x32_f16(xh[0][3], B3, h0, 0, 0, 0);           \
    h1 = __builtin_amdgcn_mfma_f32_16x16x32_f16(xh[1][3], B3, h1, 0, 0, 0);           \
    l0 = __builtin_amdgcn_mfma_f32_16x16x32_f16(xl[0][3], B3, l0, 0, 0, 0);           \
    l1 = __builtin_amdgcn_mfma_f32_16x16x32_f16(xl[1][3], B3, l1, 0, 0, 0);           \
    _Pragma("unroll")                                                                 \
    for (int rg = 0; rg < 4; ++rg) {                                                  \
        float sc0 = h0[rg] + l0[rg];                                                  \
        sec[0][rg]  = __builtin_amdgcn_fmed3f(best[0][rg], sec[0][rg], sc0);          \
        bidx[0][rg] = (sc0 > best[0][rg]) ? code_ : bidx[0][rg];                      \
        best[0][rg] = fmaxf(best[0][rg], sc0);                                        \
        float sc1 = h1[rg] + l1[rg];                                                  \
        sec[1][rg]  = __builtin_amdgcn_fmed3f(best[1][rg], sec[1][rg], sc1);          \
        bidx[1][rg] = (sc1 > best[1][rg]) ? code_ : bidx[1][rg];                      \
        best[1][rg] = fmaxf(best[1][rg], sc1);                                        \
    }                                                                                 \
} while (0)

    int curb = 0;
#pragma unroll 1
    for (int kt = 0; kt < NCHUNKS; ++kt) {
        // stage next chunk into the other buffer (issued BEFORE compute; its
        // vmcnt drain happens at the end-of-iteration barrier, a full compute later)
        if (kt + 1 < NCHUNKS) {
            const _Float16* gsrc = Ehp + (size_t)(kt + 1) * CH_HALFS
                                       + (size_t)w * 2048 + (size_t)lane * 8;
            _Float16* ldst = &ebuf[curb ^ 1][w * 2048];
#pragma unroll
            for (int ks = 0; ks < 4; ++ks)
                gl_lds16(gsrc + ks * 512, ldst + ks * 512);
        }
        const _Float16* eb = &ebuf[curb][0];
        float e0 = enorm_l[kt * 64 + n];
        float e1 = enorm_l[kt * 64 + 16 + n];
        float e2 = enorm_l[kt * 64 + 32 + n];
        float e3 = enorm_l[kt * 64 + 48 + n];
        PROC(kt * 4 + 0, eb, e0);
        PROC(kt * 4 + 1, eb + 2048, e1);
        PROC(kt * 4 + 2, eb + 4096, e2);
        PROC(kt * 4 + 3, eb + 6144, e3);
        __syncthreads();   // stage visible + cur-buffer reads done before reuse
        curb ^= 1;
    }
#undef PROC

    // reduce top-2 across the 16 col classes (lane bits 0..3)
#pragma unroll
    for (int mask = 1; mask < 16; mask <<= 1) {
#pragma unroll
        for (int s = 0; s < 2; ++s)
#pragma unroll
            for (int rg = 0; rg < 4; ++rg) {
                float ob = __shfl_xor(best[s][rg], mask);
                float os = __shfl_xor(sec[s][rg], mask);
                int   oi = __shfl_xor(bidx[s][rg], mask);
                if (ob > best[s][rg] || (ob == best[s][rg] && oi < bidx[s][rg])) {
                    sec[s][rg] = fmaxf(best[s][rg], os);
                    best[s][rg] = ob; bidx[s][rg] = oi;
                } else {
                    sec[s][rg] = fmaxf(sec[s][rg], ob);
                }
            }
    }
    if (n == 0) {
#pragma unroll
        for (int s = 0; s < 2; ++s)
#pragma unroll
            for (int rg = 0; rg < 4; ++rg) {
                int r = w * 32 + s * 16 + q * 4 + rg;
                idx_l[r] = bidx[s][rg];
                if (best[s][rg] - sec[s][rg] < TAU_ACC) {
                    int p = atomicAdd(&fcnt, 1);
                    flist[p] = r;
                }
            }
    }
    __syncthreads();

    // exact fp32 refine for near-tie rows, COOPERATIVE: all 256 threads per row
    // (lane handles 4 codes; per-code arithmetic identical to passing kernel)
    int nf = fcnt;
    for (int f = 0; f < nf; ++f) {
        int r = flist[f];
        const float4* xg4 = (const float4*)(x + (row0 + r) * DIM);
        float b = -3.4e38f; int bi = 0;
        int cbase = w * 256 + lane * 4;
        for (int c = cbase; c < cbase + 4; ++c) {
            const float4* eg4 = (const float4*)(embed + (size_t)c * DIM);
            float s = 0.f;
#pragma unroll 8
            for (int d = 0; d < DIM / 4; ++d) {
                float4 xv = xg4[d], ev = eg4[d];
                s = fmaf(xv.x, ev.x, s); s = fmaf(xv.y, ev.y, s);
                s = fmaf(xv.z, ev.z, s); s = fmaf(xv.w, ev.w, s);
            }
            float sc = fmaf(2.f, s, -enorm[c]);
            if (sc > b) { b = sc; bi = c; }
        }
#pragma unroll
        for (int mask = 1; mask < 64; mask <<= 1) {
            float ob = __shfl_xor(b, mask);
            int   oi = __shfl_xor(bi, mask);
            if (ob > b || (ob == b && oi < bi)) { b = ob; bi = oi; }
        }
        if (lane == 0) { rbest[w] = b; rbidx[w] = bi; }
        __syncthreads();
        if (tid == 0) {
            float B = rbest[0]; int BI = rbidx[0];
#pragma unroll
            for (int i = 1; i < 4; ++i)
                if (rbest[i] > B || (rbest[i] == B && rbidx[i] < BI)) { B = rbest[i]; BI = rbidx[i]; }
            idx_l[r] = BI;
        }
        __syncthreads();
    }
    __syncthreads();

    // fused gather (embed L2-resident) + float index write
    const float4* e4 = (const float4*)embed;
    float4* oq4 = (float4*)outq + row0 * (DIM / 4);
#pragma unroll
    for (int i = 0; i < 16; ++i) {
        int g = tid + i * 256;
        int r = g >> 5, d4 = g & 31;
        int id = idx_l[r];
        oq4[g] = e4[(size_t)id * (DIM / 4) + d4];
    }
    if (tid < BROWS) outi[row0 + tid] = (float)idx_l[tid];
}

extern "C" void kernel_launch(void* const* d_in, const int* in_sizes, int n_in,
                              void* d_out, int out_size, void* d_ws, size_t ws_size,
                              hipStream_t stream) {
    const float* x     = (const float*)d_in[0];
    const float* embed = (const float*)d_in[1];
    const int x_elems  = in_sizes[0];          // 12,288,000
    const int n_rows   = x_elems / DIM;        // 96,000

    float*    enorm = (float*)d_ws;                              // 4 KB
    _Float16* Ehp   = (_Float16*)((char*)d_ws + 4096);           // 256 KB

    float* outq = (float*)d_out;
    float* outi = (float*)d_out + (size_t)x_elems;

    enorm_kernel<<<KCODES / 256, 256, 0, stream>>>(embed, enorm);
    pack_kernel<<<KCODES * 16 / 256, 256, 0, stream>>>(embed, Ehp);
    argmax_mfma_kernel<<<n_rows / BROWS, 256, 0, stream>>>(x, embed, Ehp, enorm, outq, outi);
}